// Round 11
// baseline (2168.299 us; speedup 1.0000x reference)
//
#include <hip/hip_runtime.h>

#define Bq   1024
#define NQS  15
#define NCS  18
#define NMSS 20
#define NPPc 36
#define NN   36864
#define DD   128
#define NTD  16
#define NP   5
#define NT   3
#define NBLK 512          // 2 batches per block

typedef __attribute__((ext_vector_type(8))) short short8;
typedef __attribute__((ext_vector_type(4))) short short4v;
typedef __attribute__((ext_vector_type(4))) float float4v;

__device__ __forceinline__ short f2bf(float f) {
  unsigned u = __builtin_bit_cast(unsigned, f);
  u = u + 0x7FFFu + ((u >> 16) & 1u);
  return (short)(u >> 16);
}
__device__ __forceinline__ float bf2f(short s) {
  unsigned u = ((unsigned)(unsigned short)s) << 16;
  return __builtin_bit_cast(float, u);
}

// XOR-swizzled LDS indices (16B groups)
__device__ __forceinline__ int hs_idx(int row, int col) {   // [96][256] bf16 (also stg [72][256])
  return (row << 8) + ((((col >> 3) ^ (row & 7)) << 3) | (col & 7));
}
__device__ __forceinline__ int as_idx(int row, int col) {   // [72][128] bf16 (actS, aggS)
  return (row << 7) + ((((col >> 3) ^ (row & 7)) << 3) | (col & 7));
}
__device__ __forceinline__ int ms_idx(int f, int e) {       // msgS [128][104] bf16, feat-major
  return f * 104 + e;
}

// LDS layout (125184 B total)
#define OFF_ACT 49152     // actS [72][128] bf16; t-phase: xsT fp32 [66][128] (spans into AGG)
#define OFF_AGG 67584     // aggS [72][128] bf16
#define OFF_UNI 86016     // stgS [72][256] bf16 / msgS [128][104] bf16 (aliased by phase)
#define OFF_FR  122880
#define OFF_TO  123648
#define OFF_EF  124416
// t-phase overlays inside HS region (offset 0..49152):
#define TO_WT1  0         // 8192 B
#define TO_WT2  8192      // 1024 B
#define TO_MQ   9216      // 2560 B
#define TO_MC   11776     // 2560 B
#define TO_LA   14336     // 3200 B
#define TO_RED  17536     // 32 B
#define TO_H1   17600     // 4224 B

struct MP {
  const float* node_f; const float* edge_f;
  const int* from_idx; const int* to_idx;
  const short *WTc1, *WTm1, *WTu1, *WTc2, *WTm2, *WTu2;  // [M][256] bf16
  const float *b_c1, *b_c2, *b_m1, *b_m2, *b_u1, *b_u2;
  const float *c_n, *d_n, *c_e, *d_e;                     // folded fp32 constants [256]
  const float *W_t1, *b_t1, *W_t2, *b_t2;
  short* blkg;   // [NN][640] bf16: blocks 1..4 (+unused tail)
  short* mixg;   // [NN][512] bf16: mixed blocks 1..4
  float* out;
};

// K=256 GEMM core with given A fragments, 6 n-tiles (96 cols).
template<int MT, typename F>
__device__ __forceinline__ void gemm_core(const short8 (&afr)[MT][8], F loadB,
                                          int quad, float4v (&acc)[MT][6]) {
#pragma unroll
  for (int mt = 0; mt < MT; ++mt)
#pragma unroll
    for (int nt = 0; nt < 6; ++nt) acc[mt][nt] = (float4v)0.f;
#pragma unroll
  for (int ks = 0; ks < 8; ++ks) {
    const int k0q = ks * 32 + quad * 8;
    short8 bfr[6];
#pragma unroll
    for (int nt = 0; nt < 6; ++nt) bfr[nt] = loadB(nt, k0q);
#pragma unroll
    for (int mt = 0; mt < MT; ++mt)
#pragma unroll
      for (int nt = 0; nt < 6; ++nt)
        acc[mt][nt] = __builtin_amdgcn_mfma_f32_16x16x32_bf16(afr[mt][ks], bfr[nt], acc[mt][nt], 0, 0, 0);
  }
}

template<int MT>
__device__ __forceinline__ void loadA(const short* __restrict__ WT, int wm, int quad, int l16,
                                      short8 (&afr)[MT][8]) {
#pragma unroll
  for (int ks = 0; ks < 8; ++ks)
#pragma unroll
    for (int mt = 0; mt < MT; ++mt)
      afr[mt][ks] = *(const short8*)(WT + (long)(wm * (MT * 16) + mt * 16 + l16) * 256
                                        + ks * 32 + quad * 8);
}

// NOTE: __launch_bounds__(512) only — the 512-thread workgroup needs 2 waves/SIMD
// to be schedulable, so the allocator naturally caps at 256 VGPRs. Declaring
// ",2" (min 2 waves/EU) capped it at 128 and SPILLED the persistent weights
// (R10: FETCH 2.4 GB of scratch traffic).
__global__ __launch_bounds__(512) void mega(MP P) {
  __shared__ __attribute__((aligned(16))) char smem[125184];
  short* HS   = (short*)smem;               // [96][256] bf16
  short* actS = (short*)(smem + OFF_ACT);
  short* aggS = (short*)(smem + OFF_AGG);
  short* stgS = (short*)(smem + OFF_UNI);   // staged comb-B [72][256]
  short* msgS = stgS;                       // [128][104] (aliased)
  int*   frS  = (int*)(smem + OFF_FR);      // [192]
  int*   toS  = (int*)(smem + OFF_TO);      // [192]
  float* efS  = (float*)(smem + OFF_EF);    // [192]
  float* xsT  = (float*)(smem + OFF_ACT);   // t-phase fp32 [2][33][128]
  float* wt1S = (float*)(smem + TO_WT1);
  float* wt2S = (float*)(smem + TO_WT2);
  float* mqS  = (float*)(smem + TO_MQ);
  float* mcS  = (float*)(smem + TO_MC);
  float* laS  = (float*)(smem + TO_LA);
  float* redS = (float*)(smem + TO_RED);
  float* h1S  = (float*)(smem + TO_H1);

  const int tid = threadIdx.x, lane = tid & 63, wm = tid >> 6;  // wm 0..7
  const int quad = lane >> 4, l16 = lane & 15;
  const int b = blockIdx.x;           // batches 2b, 2b+1
  const long nb = (long)b * 72;

  // persistent msg weights (constant across all t/p): 96 VGPRs
  short8 wm1p[2][8], wm2p[1][8];
  loadA<2>(P.WTm1, wm, quad, l16, wm1p);
  loadA<1>(P.WTm2, wm, quad, l16, wm2p);

  // stage edge topology (t-invariant)
  for (int j = tid; j < 192; j += 512) {
    int c = j / 96, jj = j - c * 96;
    if (jj < 90) {
      int e = (b * 2 + c) * 135 + jj;
      frS[j] = P.from_idx[e] - (int)nb;
      toS[j] = P.to_idx[e] - (int)nb;
      efS[j] = P.edge_f[e];
    } else { frS[j] = 0; toS[j] = -1; efS[j] = 0.f; }
  }
  __syncthreads();

  for (int t = 0; t < NT; ++t) {
    for (int p_ = (t == 0 ? 1 : 2); p_ <= NP; ++p_) {
      // ========== P1: comb L1 -> HS ==========
      if (p_ == 1) {
        for (int i = tid; i < 96 * 256; i += 512) {
          int node = i >> 8, h = i & 255;
          int nc = node < 72 ? node : 71;
          float nf = P.node_f[nb + nc];
          float v = nf * P.c_n[h] + P.d_n[h] + P.b_c1[h];
          HS[hs_idx(node, h)] = f2bf(v > 0.f ? v : 0.f);
        }
      } else {
        short8 a1[2][8];
        loadA<2>(P.WTc1, wm, quad, l16, a1);
        float4v acc[2][6];
        gemm_core<2>(a1, [&](int nt, int k0q) -> short8 {
          int n = nt * 16 + l16; int nc = n < 72 ? n : 71;
          return *(const short8*)(&stgS[hs_idx(nc, k0q)]);
        }, quad, acc);
#pragma unroll
        for (int mt = 0; mt < 2; ++mt) {
          const int h0 = wm * 32 + mt * 16 + quad * 4;
          float4v bv = *(const float4v*)(P.b_c1 + h0);
#pragma unroll
          for (int nt = 0; nt < 6; ++nt) {
            const int col = nt * 16 + l16;
            short4v hv;
#pragma unroll
            for (int r = 0; r < 4; ++r) {
              float v = acc[mt][nt][r] + bv[r];
              hv[r] = f2bf(v > 0.f ? v : 0.f);
            }
            *(short4v*)(&HS[hs_idx(col, h0)]) = hv;
          }
        }
      }
      __syncthreads();
      // ========== P2: comb L2 -> actS ==========
      {
        short8 a2[1][8];
        loadA<1>(P.WTc2, wm, quad, l16, a2);
        float4v acc2[1][6];
        gemm_core<1>(a2, [&](int nt, int k0q) -> short8 {
          return *(const short8*)(&HS[hs_idx(nt * 16 + l16, k0q)]);
        }, quad, acc2);
        const int f0 = wm * 16 + quad * 4;
        float4v bv = *(const float4v*)(P.b_c2 + f0);
#pragma unroll
        for (int nt = 0; nt < 6; ++nt) {
          int node = nt * 16 + l16;
          if (node < 72) {
            short4v ov;
#pragma unroll
            for (int r = 0; r < 4; ++r) ov[r] = f2bf(acc2[0][nt][r] + bv[r]);
            *(short4v*)(&actS[as_idx(node, f0)]) = ov;
          }
        }
      }
      __syncthreads();
      // ========== msg chunks (96 edges each) ==========
#pragma unroll
      for (int c2 = 0; c2 < 2; ++c2) {
        // msg L1 (persistent wm1p) -> HS
        {
          int fa[6], ta[6]; float ev[6];
#pragma unroll
          for (int nt = 0; nt < 6; ++nt) {
            int j = c2 * 96 + nt * 16 + l16;
            fa[nt] = frS[j] < 0 ? 0 : frS[j];
            int tv = toS[j];
            ta[nt] = tv < 0 ? 0 : tv;
            ev[nt] = efS[j];
          }
          float4v acc[2][6];
          gemm_core<2>(wm1p, [&](int nt, int k0q) -> short8 {
            return (k0q < 128) ? *(const short8*)(&actS[as_idx(fa[nt], k0q)])
                               : *(const short8*)(&actS[as_idx(ta[nt], k0q - 128)]);
          }, quad, acc);
#pragma unroll
          for (int mt = 0; mt < 2; ++mt) {
            const int h0 = wm * 32 + mt * 16 + quad * 4;
            float4v bv = *(const float4v*)(P.b_m1 + h0);
            float4v ce = *(const float4v*)(P.c_e + h0);
            float4v de = *(const float4v*)(P.d_e + h0);
#pragma unroll
            for (int nt = 0; nt < 6; ++nt) {
              const int col = nt * 16 + l16;
              short4v hv;
#pragma unroll
              for (int r = 0; r < 4; ++r) {
                float v = acc[mt][nt][r] + bv[r] + de[r] + ev[nt] * ce[r];
                hv[r] = f2bf(v > 0.f ? v : 0.f);
              }
              *(short4v*)(&HS[hs_idx(col, h0)]) = hv;
            }
          }
        }
        __syncthreads();
        // msg L2 (persistent wm2p) -> msgS
        {
          float4v acc2[1][6];
          gemm_core<1>(wm2p, [&](int nt, int k0q) -> short8 {
            return *(const short8*)(&HS[hs_idx(nt * 16 + l16, k0q)]);
          }, quad, acc2);
          const int f0 = wm * 16 + quad * 4;
          float4v bv = *(const float4v*)(P.b_m2 + f0);
#pragma unroll
          for (int nt = 0; nt < 6; ++nt) {
            int e = nt * 16 + l16;
#pragma unroll
            for (int r = 0; r < 4; ++r)
              msgS[ms_idx(f0 + r, e)] = f2bf(acc2[0][nt][r] + bv[r]);
          }
        }
        __syncthreads();
        // agg chunk c2 (reads msgS)
        {
          float4v ag[3];
#pragma unroll
          for (int nt = 0; nt < 3; ++nt) ag[nt] = (float4v)0.f;
          const short ONE = (short)0x3F80;
#pragma unroll
          for (int ks = 0; ks < 3; ++ks) {
            const int k0 = ks * 32 + quad * 8;
            short8 a0 = *(const short8*)(&msgS[ms_idx(wm * 16 + l16, k0)]);
            int tv[8];
#pragma unroll
            for (int j = 0; j < 8; ++j) tv[j] = toS[c2 * 96 + k0 + j];
#pragma unroll
            for (int nt = 0; nt < 3; ++nt) {
              const int node = c2 * 36 + nt * 16 + l16;
              short8 bfr;
#pragma unroll
              for (int j = 0; j < 8; ++j) bfr[j] = (tv[j] == node) ? ONE : (short)0;
              ag[nt] = __builtin_amdgcn_mfma_f32_16x16x32_bf16(a0, bfr, ag[nt], 0, 0, 0);
            }
          }
          const int f0 = wm * 16 + quad * 4;
#pragma unroll
          for (int nt = 0; nt < 3; ++nt) {
            int local = nt * 16 + l16;
            if (local < 36) {
              short4v ov;
#pragma unroll
              for (int r = 0; r < 4; ++r) ov[r] = f2bf(ag[nt][r]);
              *(short4v*)(&aggS[as_idx(c2 * 36 + local, f0)]) = ov;
            }
          }
        }
        __syncthreads();
      }
      // ========== upd L1 -> HS (+ stage mixg half for next p) ==========
      {
        if (p_ < 5) {
          for (int i = tid; i < 72 * 16; i += 512) {
            int row = i >> 4, col = (i & 15) << 3;
            short8 v = *(const short8*)(P.mixg + (nb + row) * 512 + (p_ - 1) * 128 + col);
            *(short8*)(&stgS[hs_idx(row, 128 + col)]) = v;
          }
        }
        short8 a1[2][8];
        loadA<2>(P.WTu1, wm, quad, l16, a1);
        float4v acc[2][6];
        gemm_core<2>(a1, [&](int nt, int k0q) -> short8 {
          int n = nt * 16 + l16; int nc = n < 72 ? n : 71;
          return (k0q < 128) ? *(const short8*)(&actS[as_idx(nc, k0q)])
                             : *(const short8*)(&aggS[as_idx(nc, k0q - 128)]);
        }, quad, acc);
#pragma unroll
        for (int mt = 0; mt < 2; ++mt) {
          const int h0 = wm * 32 + mt * 16 + quad * 4;
          float4v bv = *(const float4v*)(P.b_u1 + h0);
#pragma unroll
          for (int nt = 0; nt < 6; ++nt) {
            const int col = nt * 16 + l16;
            short4v hv;
#pragma unroll
            for (int r = 0; r < 4; ++r) {
              float v = acc[mt][nt][r] + bv[r];
              hv[r] = f2bf(v > 0.f ? v : 0.f);
            }
            *(short4v*)(&HS[hs_idx(col, h0)]) = hv;
          }
        }
      }
      __syncthreads();
      // ========== upd L2 -> blkg+stgS (p<5) or xsT fp32 (p==5) ==========
      {
        short8 a2[1][8];
        loadA<1>(P.WTu2, wm, quad, l16, a2);
        float4v acc2[1][6];
        gemm_core<1>(a2, [&](int nt, int k0q) -> short8 {
          return *(const short8*)(&HS[hs_idx(nt * 16 + l16, k0q)]);
        }, quad, acc2);
        const int f0 = wm * 16 + quad * 4;
        float4v bv = *(const float4v*)(P.b_u2 + f0);
#pragma unroll
        for (int nt = 0; nt < 6; ++nt) {
          int node = nt * 16 + l16;
          if (node < 72) {
            if (p_ < 5) {
              short4v ov;
#pragma unroll
              for (int r = 0; r < 4; ++r) ov[r] = f2bf(acc2[0][nt][r] + bv[r]);
              *(short4v*)(P.blkg + (nb + node) * 640 + (p_ - 1) * 128 + f0) = ov;
              *(short4v*)(&stgS[hs_idx(node, f0)]) = ov;
            } else {
              int bb = node / 36, n36 = node - bb * 36;
              if (n36 < 15 || n36 >= 18) {
                int row = (n36 < 15) ? n36 : n36 - 3;
                float4v xv;
#pragma unroll
                for (int r = 0; r < 4; ++r) xv[r] = acc2[0][nt][r] + bv[r];
                *(float4v*)(&xsT[(bb * 33 + row) * 128 + f0]) = xv;
              }
            }
          }
        }
      }
      __syncthreads();
    }  // p loop

    // ================= t-phase =================
    for (int i = tid; i < 2048; i += 512) wt1S[i] = P.W_t1[i];
    if (tid < 256) wt2S[tid] = P.W_t2[tid];
    for (int i = tid; i < 2 * NMSS * NTD; i += 512) {
      int r = (i % 320) >> 4;
      if (r >= NQS) mqS[i] = 0.f;
      if (r >= NCS) mcS[i] = 0.f;
    }
    __syncthreads();
    for (int i = tid; i < 2 * 33 * NTD; i += 512) {
      int r2 = i / NTD, c = i % NTD;
      float s = P.b_t1[c];
      for (int k = 0; k < 128; ++k) s += xsT[r2 * 128 + k] * wt1S[k * NTD + c];
      h1S[i] = s > 0.f ? s : 0.f;
    }
    __syncthreads();
    for (int i = tid; i < 2 * 33 * NTD; i += 512) {
      int r2 = i / NTD, c = i % NTD;
      int bb = r2 / 33, r = r2 - bb * 33;
      float s = P.b_t2[c];
      for (int k = 0; k < NTD; ++k) s += h1S[r2 * NTD + k] * wt2S[k * NTD + c];
      if (r < NQS) mqS[bb * 320 + r * NTD + c] = s;
      else         mcS[bb * 320 + (r - NQS) * NTD + c] = s;
    }
    __syncthreads();
    for (int i = tid; i < 800; i += 512) {
      int bb = i / 400, qc = i - bb * 400;
      int q = qc / 20, c = qc - q * 20;
      float s = 0.f;
      for (int k = 0; k < NTD; ++k) s += mqS[bb * 320 + q * NTD + k] * mcS[bb * 320 + c * NTD + k];
      laS[i] = s * 10.f;  // / SINKHORN_TEMP
    }
    __syncthreads();
    for (int it = 0; it < 10; ++it) {
      if (tid < 40) {
        int bb = tid / 20, q = tid - bb * 20;
        float* la = laS + bb * 400;
        float m = -1e30f;
        for (int c = 0; c < 20; ++c) m = fmaxf(m, la[q * 20 + c]);
        float s = 0.f;
        for (int c = 0; c < 20; ++c) s += expf(la[q * 20 + c] - m);
        float l = m + logf(s);
        for (int c = 0; c < 20; ++c) la[q * 20 + c] -= l;
      }
      __syncthreads();
      if (tid < 40) {
        int bb = tid / 20, c = tid - bb * 20;
        float* la = laS + bb * 400;
        float m = -1e30f;
        for (int q = 0; q < 20; ++q) m = fmaxf(m, la[q * 20 + c]);
        float s = 0.f;
        for (int q = 0; q < 20; ++q) s += expf(la[q * 20 + c] - m);
        float l = m + logf(s);
        for (int q = 0; q < 20; ++q) la[q * 20 + c] -= l;
      }
      __syncthreads();
    }
    for (int i = tid; i < 800; i += 512) laS[i] = expf(laS[i]);
    __syncthreads();
    if (t < NT - 1) {
      // mix -> mixg; also fill stgS for next-t p=2 (cols 0..127 blk1, 128..255 mixed1)
      for (int f = tid; f < 512; f += 512) {
        for (int bb = 0; bb < 2; ++bb) {
          const float* pl = laS + bb * 400;
          long rb = nb + bb * 36;
          short rq[18], rc[18];
          float oq[18], oc[18];
          for (int j = 0; j < 18; ++j) {
            rq[j] = P.blkg[(rb + j) * 640 + f];
            rc[j] = P.blkg[(rb + 18 + j) * 640 + f];
            oq[j] = bf2f(rq[j]); oc[j] = bf2f(rc[j]);
          }
          for (int j = 0; j < 18; ++j) {
            float aq = 0.f, ac = 0.f;
            for (int k = 0; k < 18; ++k) {
              aq += pl[j * 20 + k] * oc[k];
              ac += pl[k * 20 + j] * oq[k];
            }
            short hq = f2bf(aq), hc = f2bf(ac);
            P.mixg[(rb + j) * 512 + f]      = hq;
            P.mixg[(rb + 18 + j) * 512 + f] = hc;
            if (f < 128) {
              stgS[hs_idx(bb * 36 + j, f)]            = rq[j];
              stgS[hs_idx(bb * 36 + 18 + j, f)]       = rc[j];
              stgS[hs_idx(bb * 36 + j, 128 + f)]      = hq;
              stgS[hs_idx(bb * 36 + 18 + j, 128 + f)] = hc;
            }
          }
        }
      }
      __syncthreads();
    } else {
      if (tid < 2) redS[tid] = 0.f;
      __syncthreads();
      float sl[2] = {0.f, 0.f};
      for (int i = tid; i < 640; i += 512) {
        int bb = i / 320, qt = i - bb * 320;
        int q = qt / 16, tt = qt & 15;
        float d = 0.f;
        for (int c = 0; c < 20; ++c) d += laS[bb * 400 + q * 20 + c] * mcS[bb * 320 + c * 16 + tt];
        float r = mqS[bb * 320 + qt] - d;
        if (r > 0.f) sl[bb] += r;
      }
      if (sl[0] != 0.f) atomicAdd(&redS[0], sl[0]);
      if (sl[1] != 0.f) atomicAdd(&redS[1], sl[1]);
      __syncthreads();
      if (tid < 2) P.out[b * 2 + tid] = -redS[tid];
    }
  }  // t loop
}

// W[K][N] fp32 -> WT[N][K] bf16
__global__ __launch_bounds__(256) void wtrans(const float* W, short* WT, int K, int N) {
  int i = blockIdx.x * 256 + threadIdx.x;
  if (i < K * N) {
    int n = i / K, k = i - n * K;
    WT[i] = f2bf(W[(long)k * N + n]);
  }
}

__global__ __launch_bounds__(256) void consts_kernel(
    const float* W_ne, const float* b_ne, const float* W_c1,
    const float* W_ee, const float* b_ee, const float* W_m1,
    float* c_n, float* d_n, float* c_e, float* d_e) {
  int h = threadIdx.x;
  float cn = 0.f, dn = 0.f, ce = 0.f, de = 0.f;
  for (int d = 0; d < 128; ++d) {
    float wc = W_c1[d * 256 + h];
    cn += W_ne[d] * wc; dn += b_ne[d] * wc;
    float wmv = W_m1[(256 + d) * 256 + h];
    ce += W_ee[d] * wmv; de += b_ee[d] * wmv;
  }
  c_n[h] = cn; d_n[h] = dn; c_e[h] = ce; d_e[h] = de;
}

extern "C" void kernel_launch(void* const* d_in, const int* in_sizes, int n_in,
                              void* d_out, int out_size, void* d_ws, size_t ws_size,
                              hipStream_t stream) {
  (void)in_sizes; (void)n_in; (void)out_size; (void)ws_size;
  const float* node_f = (const float*)d_in[0];
  const float* edge_f = (const float*)d_in[1];
  const float* W_ne   = (const float*)d_in[3];
  const float* b_ne   = (const float*)d_in[4];
  const float* W_ee   = (const float*)d_in[5];
  const float* b_ee   = (const float*)d_in[6];
  const float* W_m1   = (const float*)d_in[7];
  const float* b_m1   = (const float*)d_in[8];
  const float* W_m2   = (const float*)d_in[9];
  const float* b_m2   = (const float*)d_in[10];
  const float* W_u1   = (const float*)d_in[11];
  const float* b_u1   = (const float*)d_in[12];
  const float* W_u2   = (const float*)d_in[13];
  const float* b_u2   = (const float*)d_in[14];
  const float* W_c1   = (const float*)d_in[15];
  const float* b_c1   = (const float*)d_in[16];
  const float* W_c2   = (const float*)d_in[17];
  const float* b_c2   = (const float*)d_in[18];
  const float* W_t1   = (const float*)d_in[19];
  const float* b_t1   = (const float*)d_in[20];
  const float* W_t2   = (const float*)d_in[21];
  const float* b_t2   = (const float*)d_in[22];
  const int* from_idx = (const int*)d_in[23];
  const int* to_idx   = (const int*)d_in[24];

  char* base = (char*)d_ws;
  size_t off = 0;
  auto alloc = [&](size_t bytes) { char* pp = base + off; off += (bytes + 255) & ~(size_t)255; return pp; };
  short* blkg = (short*)alloc((size_t)NN * 640 * 2);
  short* mixg = (short*)alloc((size_t)NN * 512 * 2);
  short* WTc1 = (short*)alloc(256 * 256 * 2);
  short* WTm1 = (short*)alloc(256 * 256 * 2);
  short* WTu1 = (short*)alloc(256 * 256 * 2);
  short* WTc2 = (short*)alloc(128 * 256 * 2);
  short* WTm2 = (short*)alloc(128 * 256 * 2);
  short* WTu2 = (short*)alloc(128 * 256 * 2);
  float* c_n  = (float*)alloc(256 * 4);
  float* d_n  = (float*)alloc(256 * 4);
  float* c_e  = (float*)alloc(256 * 4);
  float* d_e  = (float*)alloc(256 * 4);

  wtrans<<<256, 256, 0, stream>>>(W_c1, WTc1, 256, 256);
  wtrans<<<256, 256, 0, stream>>>(W_m1, WTm1, 256, 256);  // first 256 K-rows (rest folded)
  wtrans<<<256, 256, 0, stream>>>(W_u1, WTu1, 256, 256);
  wtrans<<<128, 256, 0, stream>>>(W_c2, WTc2, 256, 128);
  wtrans<<<128, 256, 0, stream>>>(W_m2, WTm2, 256, 128);
  wtrans<<<128, 256, 0, stream>>>(W_u2, WTu2, 256, 128);
  consts_kernel<<<1, 256, 0, stream>>>(W_ne, b_ne, W_c1, W_ee, b_ee, W_m1, c_n, d_n, c_e, d_e);
  hipMemsetAsync(mixg, 0, (size_t)NN * 512 * 2, stream);

  MP mp{};
  mp.node_f = node_f; mp.edge_f = edge_f;
  mp.from_idx = from_idx; mp.to_idx = to_idx;
  mp.WTc1 = WTc1; mp.WTm1 = WTm1; mp.WTu1 = WTu1;
  mp.WTc2 = WTc2; mp.WTm2 = WTm2; mp.WTu2 = WTu2;
  mp.b_c1 = b_c1; mp.b_c2 = b_c2; mp.b_m1 = b_m1; mp.b_m2 = b_m2;
  mp.b_u1 = b_u1; mp.b_u2 = b_u2;
  mp.c_n = c_n; mp.d_n = d_n; mp.c_e = c_e; mp.d_e = d_e;
  mp.W_t1 = W_t1; mp.b_t1 = b_t1; mp.W_t2 = W_t2; mp.b_t2 = b_t2;
  mp.blkg = blkg; mp.mixg = mixg; mp.out = (float*)d_out;

  mega<<<NBLK, 512, 0, stream>>>(mp);
}

// Round 12
// 1597.934 us; speedup vs baseline: 1.3569x; 1.3569x over previous
//
#include <hip/hip_runtime.h>

#define Bq   1024
#define NQS  15
#define NCS  18
#define NMSS 20
#define NPPc 36
#define NN   36864
#define DD   128
#define NTD  16
#define NP   5
#define NT   3
#define NBLK 512          // 2 batches per block

typedef __attribute__((ext_vector_type(8))) short short8;
typedef __attribute__((ext_vector_type(4))) short short4v;
typedef __attribute__((ext_vector_type(4))) float float4v;

__device__ __forceinline__ short f2bf(float f) {
  unsigned u = __builtin_bit_cast(unsigned, f);
  u = u + 0x7FFFu + ((u >> 16) & 1u);
  return (short)(u >> 16);
}
__device__ __forceinline__ float bf2f(short s) {
  unsigned u = ((unsigned)(unsigned short)s) << 16;
  return __builtin_bit_cast(float, u);
}

// XOR-swizzled LDS indices (16B groups)
__device__ __forceinline__ int hs_idx(int row, int col) {   // [96][256] bf16 (also stg [72][256])
  return (row << 8) + ((((col >> 3) ^ (row & 7)) << 3) | (col & 7));
}
__device__ __forceinline__ int as_idx(int row, int col) {   // [72][128] bf16 (actS, aggS)
  return (row << 7) + ((((col >> 3) ^ (row & 7)) << 3) | (col & 7));
}
__device__ __forceinline__ int ms_idx(int f, int e) {       // msgS [128][104] bf16, feat-major
  return f * 104 + e;
}

// LDS layout (125184 B total)
#define OFF_ACT 49152     // actS [72][128] bf16; t-phase: xsT fp32 [66][128] (spans into AGG)
#define OFF_AGG 67584     // aggS [72][128] bf16
#define OFF_UNI 86016     // stgS [72][256] bf16 / msgS [128][104] bf16 (aliased by phase)
#define OFF_FR  122880
#define OFF_TO  123648
#define OFF_EF  124416
// t-phase overlays inside HS region (offset 0..49152):
#define TO_WT1  0         // 8192 B
#define TO_WT2  8192      // 1024 B
#define TO_MQ   9216      // 2560 B
#define TO_MC   11776     // 2560 B
#define TO_LA   14336     // 3200 B
#define TO_RED  17536     // 32 B
#define TO_H1   17600     // 4224 B

struct MP {
  const float* node_f; const float* edge_f;
  const int* from_idx; const int* to_idx;
  const short *WTc1, *WTm1, *WTu1, *WTc2, *WTm2, *WTu2;  // [M][256] bf16
  const float *b_c1, *b_c2, *b_m1, *b_m2, *b_u1, *b_u2;
  const float *c_n, *d_n, *c_e, *d_e;                     // folded fp32 constants [256]
  const float *W_t1, *b_t1, *W_t2, *b_t2;
  short* blkg;   // [NN][640] bf16: blocks 1..4 (+unused tail)
  short* mixg;   // [NN][512] bf16: mixed blocks 1..4
  float* out;
};

// K=256 GEMM core with given A fragments, 6 n-tiles (96 cols).
template<int MT, typename F>
__device__ __forceinline__ void gemm_core(const short8 (&afr)[MT][8], F loadB,
                                          int quad, float4v (&acc)[MT][6]) {
#pragma unroll
  for (int mt = 0; mt < MT; ++mt)
#pragma unroll
    for (int nt = 0; nt < 6; ++nt) acc[mt][nt] = (float4v)0.f;
#pragma unroll
  for (int ks = 0; ks < 8; ++ks) {
    const int k0q = ks * 32 + quad * 8;
    short8 bfr[6];
#pragma unroll
    for (int nt = 0; nt < 6; ++nt) bfr[nt] = loadB(nt, k0q);
#pragma unroll
    for (int mt = 0; mt < MT; ++mt)
#pragma unroll
      for (int nt = 0; nt < 6; ++nt)
        acc[mt][nt] = __builtin_amdgcn_mfma_f32_16x16x32_bf16(afr[mt][ks], bfr[nt], acc[mt][nt], 0, 0, 0);
  }
}

template<int MT>
__device__ __forceinline__ void loadA(const short* __restrict__ WT, int wm, int quad, int l16,
                                      short8 (&afr)[MT][8]) {
#pragma unroll
  for (int ks = 0; ks < 8; ++ks)
#pragma unroll
    for (int mt = 0; mt < MT; ++mt)
      afr[mt][ks] = *(const short8*)(WT + (long)(wm * (MT * 16) + mt * 16 + l16) * 256
                                        + ks * 32 + quad * 8);
}

// R10/R11 lesson: 96 VGPRs of "persistent" weights at a 128-reg cap = scratch
// spills (+1.6 GB FETCH). Per-phase loads fit the 128-reg working set spill-free.
__global__ __launch_bounds__(512) __attribute__((amdgpu_waves_per_eu(2, 2)))
void mega(MP P) {
  __shared__ __attribute__((aligned(16))) char smem[125184];
  short* HS   = (short*)smem;               // [96][256] bf16
  short* actS = (short*)(smem + OFF_ACT);
  short* aggS = (short*)(smem + OFF_AGG);
  short* stgS = (short*)(smem + OFF_UNI);   // staged comb-B [72][256]
  short* msgS = stgS;                       // [128][104] (aliased)
  int*   frS  = (int*)(smem + OFF_FR);      // [192]
  int*   toS  = (int*)(smem + OFF_TO);      // [192]
  float* efS  = (float*)(smem + OFF_EF);    // [192]
  float* xsT  = (float*)(smem + OFF_ACT);   // t-phase fp32 [2][33][128]
  float* wt1S = (float*)(smem + TO_WT1);
  float* wt2S = (float*)(smem + TO_WT2);
  float* mqS  = (float*)(smem + TO_MQ);
  float* mcS  = (float*)(smem + TO_MC);
  float* laS  = (float*)(smem + TO_LA);
  float* redS = (float*)(smem + TO_RED);
  float* h1S  = (float*)(smem + TO_H1);

  const int tid = threadIdx.x, lane = tid & 63, wm = tid >> 6;  // wm 0..7
  const int quad = lane >> 4, l16 = lane & 15;
  const int b = blockIdx.x;           // batches 2b, 2b+1
  const long nb = (long)b * 72;

  // stage edge topology (t-invariant)
  for (int j = tid; j < 192; j += 512) {
    int c = j / 96, jj = j - c * 96;
    if (jj < 90) {
      int e = (b * 2 + c) * 135 + jj;
      frS[j] = P.from_idx[e] - (int)nb;
      toS[j] = P.to_idx[e] - (int)nb;
      efS[j] = P.edge_f[e];
    } else { frS[j] = 0; toS[j] = -1; efS[j] = 0.f; }
  }
  __syncthreads();

  for (int t = 0; t < NT; ++t) {
    for (int p_ = (t == 0 ? 1 : 2); p_ <= NP; ++p_) {
      // ========== P1: comb L1 -> HS ==========
      if (p_ == 1) {
        for (int i = tid; i < 96 * 256; i += 512) {
          int node = i >> 8, h = i & 255;
          int nc = node < 72 ? node : 71;
          float nf = P.node_f[nb + nc];
          float v = nf * P.c_n[h] + P.d_n[h] + P.b_c1[h];
          HS[hs_idx(node, h)] = f2bf(v > 0.f ? v : 0.f);
        }
      } else {
        short8 a1[2][8];
        loadA<2>(P.WTc1, wm, quad, l16, a1);
        float4v acc[2][6];
        gemm_core<2>(a1, [&](int nt, int k0q) -> short8 {
          int n = nt * 16 + l16; int nc = n < 72 ? n : 71;
          return *(const short8*)(&stgS[hs_idx(nc, k0q)]);
        }, quad, acc);
#pragma unroll
        for (int mt = 0; mt < 2; ++mt) {
          const int h0 = wm * 32 + mt * 16 + quad * 4;
          float4v bv = *(const float4v*)(P.b_c1 + h0);
#pragma unroll
          for (int nt = 0; nt < 6; ++nt) {
            const int col = nt * 16 + l16;
            short4v hv;
#pragma unroll
            for (int r = 0; r < 4; ++r) {
              float v = acc[mt][nt][r] + bv[r];
              hv[r] = f2bf(v > 0.f ? v : 0.f);
            }
            *(short4v*)(&HS[hs_idx(col, h0)]) = hv;
          }
        }
      }
      __syncthreads();
      // ========== P2: comb L2 -> actS ==========
      {
        short8 a2[1][8];
        loadA<1>(P.WTc2, wm, quad, l16, a2);
        float4v acc2[1][6];
        gemm_core<1>(a2, [&](int nt, int k0q) -> short8 {
          return *(const short8*)(&HS[hs_idx(nt * 16 + l16, k0q)]);
        }, quad, acc2);
        const int f0 = wm * 16 + quad * 4;
        float4v bv = *(const float4v*)(P.b_c2 + f0);
#pragma unroll
        for (int nt = 0; nt < 6; ++nt) {
          int node = nt * 16 + l16;
          if (node < 72) {
            short4v ov;
#pragma unroll
            for (int r = 0; r < 4; ++r) ov[r] = f2bf(acc2[0][nt][r] + bv[r]);
            *(short4v*)(&actS[as_idx(node, f0)]) = ov;
          }
        }
      }
      __syncthreads();
      // ========== msg chunks (96 edges each) ==========
      for (int c2 = 0; c2 < 2; ++c2) {
        // msg L1 -> HS
        {
          int fa[6], ta[6]; float ev[6];
#pragma unroll
          for (int nt = 0; nt < 6; ++nt) {
            int j = c2 * 96 + nt * 16 + l16;
            fa[nt] = frS[j] < 0 ? 0 : frS[j];
            int tv = toS[j];
            ta[nt] = tv < 0 ? 0 : tv;
            ev[nt] = efS[j];
          }
          short8 a1[2][8];
          loadA<2>(P.WTm1, wm, quad, l16, a1);
          float4v acc[2][6];
          gemm_core<2>(a1, [&](int nt, int k0q) -> short8 {
            return (k0q < 128) ? *(const short8*)(&actS[as_idx(fa[nt], k0q)])
                               : *(const short8*)(&actS[as_idx(ta[nt], k0q - 128)]);
          }, quad, acc);
#pragma unroll
          for (int mt = 0; mt < 2; ++mt) {
            const int h0 = wm * 32 + mt * 16 + quad * 4;
            float4v bv = *(const float4v*)(P.b_m1 + h0);
            float4v ce = *(const float4v*)(P.c_e + h0);
            float4v de = *(const float4v*)(P.d_e + h0);
#pragma unroll
            for (int nt = 0; nt < 6; ++nt) {
              const int col = nt * 16 + l16;
              short4v hv;
#pragma unroll
              for (int r = 0; r < 4; ++r) {
                float v = acc[mt][nt][r] + bv[r] + de[r] + ev[nt] * ce[r];
                hv[r] = f2bf(v > 0.f ? v : 0.f);
              }
              *(short4v*)(&HS[hs_idx(col, h0)]) = hv;
            }
          }
        }
        __syncthreads();
        // msg L2 -> msgS
        {
          short8 a2[1][8];
          loadA<1>(P.WTm2, wm, quad, l16, a2);
          float4v acc2[1][6];
          gemm_core<1>(a2, [&](int nt, int k0q) -> short8 {
            return *(const short8*)(&HS[hs_idx(nt * 16 + l16, k0q)]);
          }, quad, acc2);
          const int f0 = wm * 16 + quad * 4;
          float4v bv = *(const float4v*)(P.b_m2 + f0);
#pragma unroll
          for (int nt = 0; nt < 6; ++nt) {
            int e = nt * 16 + l16;
#pragma unroll
            for (int r = 0; r < 4; ++r)
              msgS[ms_idx(f0 + r, e)] = f2bf(acc2[0][nt][r] + bv[r]);
          }
        }
        __syncthreads();
        // agg chunk c2 (reads msgS)
        {
          float4v ag[3];
#pragma unroll
          for (int nt = 0; nt < 3; ++nt) ag[nt] = (float4v)0.f;
          const short ONE = (short)0x3F80;
#pragma unroll
          for (int ks = 0; ks < 3; ++ks) {
            const int k0 = ks * 32 + quad * 8;
            short8 a0 = *(const short8*)(&msgS[ms_idx(wm * 16 + l16, k0)]);
            int tv[8];
#pragma unroll
            for (int j = 0; j < 8; ++j) tv[j] = toS[c2 * 96 + k0 + j];
#pragma unroll
            for (int nt = 0; nt < 3; ++nt) {
              const int node = c2 * 36 + nt * 16 + l16;
              short8 bfr;
#pragma unroll
              for (int j = 0; j < 8; ++j) bfr[j] = (tv[j] == node) ? ONE : (short)0;
              ag[nt] = __builtin_amdgcn_mfma_f32_16x16x32_bf16(a0, bfr, ag[nt], 0, 0, 0);
            }
          }
          const int f0 = wm * 16 + quad * 4;
#pragma unroll
          for (int nt = 0; nt < 3; ++nt) {
            int local = nt * 16 + l16;
            if (local < 36) {
              short4v ov;
#pragma unroll
              for (int r = 0; r < 4; ++r) ov[r] = f2bf(ag[nt][r]);
              *(short4v*)(&aggS[as_idx(c2 * 36 + local, f0)]) = ov;
            }
          }
        }
        __syncthreads();
      }
      // ========== upd L1 -> HS (+ stage mixg half for next p) ==========
      {
        if (p_ < 5) {
          for (int i = tid; i < 72 * 16; i += 512) {
            int row = i >> 4, col = (i & 15) << 3;
            short8 v = *(const short8*)(P.mixg + (nb + row) * 512 + (p_ - 1) * 128 + col);
            *(short8*)(&stgS[hs_idx(row, 128 + col)]) = v;
          }
        }
        short8 a1[2][8];
        loadA<2>(P.WTu1, wm, quad, l16, a1);
        float4v acc[2][6];
        gemm_core<2>(a1, [&](int nt, int k0q) -> short8 {
          int n = nt * 16 + l16; int nc = n < 72 ? n : 71;
          return (k0q < 128) ? *(const short8*)(&actS[as_idx(nc, k0q)])
                             : *(const short8*)(&aggS[as_idx(nc, k0q - 128)]);
        }, quad, acc);
#pragma unroll
        for (int mt = 0; mt < 2; ++mt) {
          const int h0 = wm * 32 + mt * 16 + quad * 4;
          float4v bv = *(const float4v*)(P.b_u1 + h0);
#pragma unroll
          for (int nt = 0; nt < 6; ++nt) {
            const int col = nt * 16 + l16;
            short4v hv;
#pragma unroll
            for (int r = 0; r < 4; ++r) {
              float v = acc[mt][nt][r] + bv[r];
              hv[r] = f2bf(v > 0.f ? v : 0.f);
            }
            *(short4v*)(&HS[hs_idx(col, h0)]) = hv;
          }
        }
      }
      __syncthreads();
      // ========== upd L2 -> blkg(NT)+stgS (p<5) or xsT fp32 (p==5) ==========
      {
        short8 a2[1][8];
        loadA<1>(P.WTu2, wm, quad, l16, a2);
        float4v acc2[1][6];
        gemm_core<1>(a2, [&](int nt, int k0q) -> short8 {
          return *(const short8*)(&HS[hs_idx(nt * 16 + l16, k0q)]);
        }, quad, acc2);
        const int f0 = wm * 16 + quad * 4;
        float4v bv = *(const float4v*)(P.b_u2 + f0);
#pragma unroll
        for (int nt = 0; nt < 6; ++nt) {
          int node = nt * 16 + l16;
          if (node < 72) {
            if (p_ < 5) {
              short4v ov;
#pragma unroll
              for (int r = 0; r < 4; ++r) ov[r] = f2bf(acc2[0][nt][r] + bv[r]);
              // blkg is NOT re-read until mix/t-phase (stgS forwards it) -> NT store
              __builtin_nontemporal_store(ov, (short4v*)(P.blkg + (nb + node) * 640 + (p_ - 1) * 128 + f0));
              *(short4v*)(&stgS[hs_idx(node, f0)]) = ov;
            } else {
              int bb = node / 36, n36 = node - bb * 36;
              if (n36 < 15 || n36 >= 18) {
                int row = (n36 < 15) ? n36 : n36 - 3;
                float4v xv;
#pragma unroll
                for (int r = 0; r < 4; ++r) xv[r] = acc2[0][nt][r] + bv[r];
                *(float4v*)(&xsT[(bb * 33 + row) * 128 + f0]) = xv;
              }
            }
          }
        }
      }
      __syncthreads();
    }  // p loop

    // ================= t-phase =================
    for (int i = tid; i < 2048; i += 512) wt1S[i] = P.W_t1[i];
    if (tid < 256) wt2S[tid] = P.W_t2[tid];
    for (int i = tid; i < 2 * NMSS * NTD; i += 512) {
      int r = (i % 320) >> 4;
      if (r >= NQS) mqS[i] = 0.f;
      if (r >= NCS) mcS[i] = 0.f;
    }
    __syncthreads();
    for (int i = tid; i < 2 * 33 * NTD; i += 512) {
      int r2 = i / NTD, c = i % NTD;
      float s = P.b_t1[c];
      for (int k = 0; k < 128; ++k) s += xsT[r2 * 128 + k] * wt1S[k * NTD + c];
      h1S[i] = s > 0.f ? s : 0.f;
    }
    __syncthreads();
    for (int i = tid; i < 2 * 33 * NTD; i += 512) {
      int r2 = i / NTD, c = i % NTD;
      int bb = r2 / 33, r = r2 - bb * 33;
      float s = P.b_t2[c];
      for (int k = 0; k < NTD; ++k) s += h1S[r2 * NTD + k] * wt2S[k * NTD + c];
      if (r < NQS) mqS[bb * 320 + r * NTD + c] = s;
      else         mcS[bb * 320 + (r - NQS) * NTD + c] = s;
    }
    __syncthreads();
    for (int i = tid; i < 800; i += 512) {
      int bb = i / 400, qc = i - bb * 400;
      int q = qc / 20, c = qc - q * 20;
      float s = 0.f;
      for (int k = 0; k < NTD; ++k) s += mqS[bb * 320 + q * NTD + k] * mcS[bb * 320 + c * NTD + k];
      laS[i] = s * 10.f;  // / SINKHORN_TEMP
    }
    __syncthreads();
    for (int it = 0; it < 10; ++it) {
      if (tid < 40) {
        int bb = tid / 20, q = tid - bb * 20;
        float* la = laS + bb * 400;
        float m = -1e30f;
        for (int c = 0; c < 20; ++c) m = fmaxf(m, la[q * 20 + c]);
        float s = 0.f;
        for (int c = 0; c < 20; ++c) s += expf(la[q * 20 + c] - m);
        float l = m + logf(s);
        for (int c = 0; c < 20; ++c) la[q * 20 + c] -= l;
      }
      __syncthreads();
      if (tid < 40) {
        int bb = tid / 20, c = tid - bb * 20;
        float* la = laS + bb * 400;
        float m = -1e30f;
        for (int q = 0; q < 20; ++q) m = fmaxf(m, la[q * 20 + c]);
        float s = 0.f;
        for (int q = 0; q < 20; ++q) s += expf(la[q * 20 + c] - m);
        float l = m + logf(s);
        for (int q = 0; q < 20; ++q) la[q * 20 + c] -= l;
      }
      __syncthreads();
    }
    for (int i = tid; i < 800; i += 512) laS[i] = expf(laS[i]);
    __syncthreads();
    if (t < NT - 1) {
      // mix -> mixg; also fill stgS for next-t p=2 (cols 0..127 blk1, 128..255 mixed1)
      for (int f = tid; f < 512; f += 512) {
        for (int bb = 0; bb < 2; ++bb) {
          const float* pl = laS + bb * 400;
          long rb = nb + bb * 36;
          short rq[18], rc[18];
          float oq[18], oc[18];
          for (int j = 0; j < 18; ++j) {
            rq[j] = P.blkg[(rb + j) * 640 + f];
            rc[j] = P.blkg[(rb + 18 + j) * 640 + f];
            oq[j] = bf2f(rq[j]); oc[j] = bf2f(rc[j]);
          }
          for (int j = 0; j < 18; ++j) {
            float aq = 0.f, ac = 0.f;
            for (int k = 0; k < 18; ++k) {
              aq += pl[j * 20 + k] * oc[k];
              ac += pl[k * 20 + j] * oq[k];
            }
            short hq = f2bf(aq), hc = f2bf(ac);
            P.mixg[(rb + j) * 512 + f]      = hq;
            P.mixg[(rb + 18 + j) * 512 + f] = hc;
            if (f < 128) {
              stgS[hs_idx(bb * 36 + j, f)]            = rq[j];
              stgS[hs_idx(bb * 36 + 18 + j, f)]       = rc[j];
              stgS[hs_idx(bb * 36 + j, 128 + f)]      = hq;
              stgS[hs_idx(bb * 36 + 18 + j, 128 + f)] = hc;
            }
          }
        }
      }
      __syncthreads();
    } else {
      if (tid < 2) redS[tid] = 0.f;
      __syncthreads();
      float sl[2] = {0.f, 0.f};
      for (int i = tid; i < 640; i += 512) {
        int bb = i / 320, qt = i - bb * 320;
        int q = qt / 16, tt = qt & 15;
        float d = 0.f;
        for (int c = 0; c < 20; ++c) d += laS[bb * 400 + q * 20 + c] * mcS[bb * 320 + c * 16 + tt];
        float r = mqS[bb * 320 + qt] - d;
        if (r > 0.f) sl[bb] += r;
      }
      if (sl[0] != 0.f) atomicAdd(&redS[0], sl[0]);
      if (sl[1] != 0.f) atomicAdd(&redS[1], sl[1]);
      __syncthreads();
      if (tid < 2) P.out[b * 2 + tid] = -redS[tid];
    }
  }  // t loop
}

// W[K][N] fp32 -> WT[N][K] bf16
__global__ __launch_bounds__(256) void wtrans(const float* W, short* WT, int K, int N) {
  int i = blockIdx.x * 256 + threadIdx.x;
  if (i < K * N) {
    int n = i / K, k = i - n * K;
    WT[i] = f2bf(W[(long)k * N + n]);
  }
}

__global__ __launch_bounds__(256) void consts_kernel(
    const float* W_ne, const float* b_ne, const float* W_c1,
    const float* W_ee, const float* b_ee, const float* W_m1,
    float* c_n, float* d_n, float* c_e, float* d_e) {
  int h = threadIdx.x;
  float cn = 0.f, dn = 0.f, ce = 0.f, de = 0.f;
  for (int d = 0; d < 128; ++d) {
    float wc = W_c1[d * 256 + h];
    cn += W_ne[d] * wc; dn += b_ne[d] * wc;
    float wmv = W_m1[(256 + d) * 256 + h];
    ce += W_ee[d] * wmv; de += b_ee[d] * wmv;
  }
  c_n[h] = cn; d_n[h] = dn; c_e[h] = ce; d_e[h] = de;
}

extern "C" void kernel_launch(void* const* d_in, const int* in_sizes, int n_in,
                              void* d_out, int out_size, void* d_ws, size_t ws_size,
                              hipStream_t stream) {
  (void)in_sizes; (void)n_in; (void)out_size; (void)ws_size;
  const float* node_f = (const float*)d_in[0];
  const float* edge_f = (const float*)d_in[1];
  const float* W_ne   = (const float*)d_in[3];
  const float* b_ne   = (const float*)d_in[4];
  const float* W_ee   = (const float*)d_in[5];
  const float* b_ee   = (const float*)d_in[6];
  const float* W_m1   = (const float*)d_in[7];
  const float* b_m1   = (const float*)d_in[8];
  const float* W_m2   = (const float*)d_in[9];
  const float* b_m2   = (const float*)d_in[10];
  const float* W_u1   = (const float*)d_in[11];
  const float* b_u1   = (const float*)d_in[12];
  const float* W_u2   = (const float*)d_in[13];
  const float* b_u2   = (const float*)d_in[14];
  const float* W_c1   = (const float*)d_in[15];
  const float* b_c1   = (const float*)d_in[16];
  const float* W_c2   = (const float*)d_in[17];
  const float* b_c2   = (const float*)d_in[18];
  const float* W_t1   = (const float*)d_in[19];
  const float* b_t1   = (const float*)d_in[20];
  const float* W_t2   = (const float*)d_in[21];
  const float* b_t2   = (const float*)d_in[22];
  const int* from_idx = (const int*)d_in[23];
  const int* to_idx   = (const int*)d_in[24];

  char* base = (char*)d_ws;
  size_t off = 0;
  auto alloc = [&](size_t bytes) { char* pp = base + off; off += (bytes + 255) & ~(size_t)255; return pp; };
  short* blkg = (short*)alloc((size_t)NN * 640 * 2);
  short* mixg = (short*)alloc((size_t)NN * 512 * 2);
  short* WTc1 = (short*)alloc(256 * 256 * 2);
  short* WTm1 = (short*)alloc(256 * 256 * 2);
  short* WTu1 = (short*)alloc(256 * 256 * 2);
  short* WTc2 = (short*)alloc(128 * 256 * 2);
  short* WTm2 = (short*)alloc(128 * 256 * 2);
  short* WTu2 = (short*)alloc(128 * 256 * 2);
  float* c_n  = (float*)alloc(256 * 4);
  float* d_n  = (float*)alloc(256 * 4);
  float* c_e  = (float*)alloc(256 * 4);
  float* d_e  = (float*)alloc(256 * 4);

  wtrans<<<256, 256, 0, stream>>>(W_c1, WTc1, 256, 256);
  wtrans<<<256, 256, 0, stream>>>(W_m1, WTm1, 256, 256);  // first 256 K-rows (rest folded)
  wtrans<<<256, 256, 0, stream>>>(W_u1, WTu1, 256, 256);
  wtrans<<<128, 256, 0, stream>>>(W_c2, WTc2, 256, 128);
  wtrans<<<128, 256, 0, stream>>>(W_m2, WTm2, 256, 128);
  wtrans<<<128, 256, 0, stream>>>(W_u2, WTu2, 256, 128);
  consts_kernel<<<1, 256, 0, stream>>>(W_ne, b_ne, W_c1, W_ee, b_ee, W_m1, c_n, d_n, c_e, d_e);
  hipMemsetAsync(mixg, 0, (size_t)NN * 512 * 2, stream);

  MP mp{};
  mp.node_f = node_f; mp.edge_f = edge_f;
  mp.from_idx = from_idx; mp.to_idx = to_idx;
  mp.WTc1 = WTc1; mp.WTm1 = WTm1; mp.WTu1 = WTu1;
  mp.WTc2 = WTc2; mp.WTm2 = WTm2; mp.WTu2 = WTu2;
  mp.b_c1 = b_c1; mp.b_c2 = b_c2; mp.b_m1 = b_m1; mp.b_m2 = b_m2;
  mp.b_u1 = b_u1; mp.b_u2 = b_u2;
  mp.c_n = c_n; mp.d_n = d_n; mp.c_e = c_e; mp.d_e = d_e;
  mp.W_t1 = W_t1; mp.b_t1 = b_t1; mp.W_t2 = W_t2; mp.b_t2 = b_t2;
  mp.blkg = blkg; mp.mixg = mixg; mp.out = (float*)d_out;

  mega<<<NBLK, 512, 0, stream>>>(mp);
}